// Round 1
// baseline (672.005 us; speedup 1.0000x reference)
//
#include <hip/hip_runtime.h>
#include <math.h>

#define B_N    1024
#define C_N    64
#define T_N    275
#define S_N    10
#define EMB_N  184
#define PROJ_N 1024
#define CT_N   (C_N * T_N)        // 17600
#define KSPLIT 16
#define KCHUNK (CT_N / KSPLIT)    // 1100
#define TK     16

__device__ __forceinline__ float gelu_exact(float v) {
    return 0.5f * v * (1.0f + erff(v * 0.70710678118654752f));
}

// ---------------------------------------------------------------------------
// K1: x[b,c,u] = sum_t eeg[b,c,t] * subj_W[sid[b],u,t] + subj_b[sid[b],u]
// grid: (ceil(T/64)=5, B), block 256
// ---------------------------------------------------------------------------
__global__ __launch_bounds__(256) void k1_subj_align(
    const float* __restrict__ eeg, const int* __restrict__ sid,
    const float* __restrict__ subj_W, const float* __restrict__ subj_b,
    float* __restrict__ x)
{
    __shared__ float As[TK][68];
    __shared__ float Bs[TK][68];
    const int b  = blockIdx.y;
    const int u0 = blockIdx.x * 64;
    const int s  = sid[b];
    const float* A = eeg    + (size_t)b * CT_N;        // [64][275]
    const float* W = subj_W + (size_t)s * T_N * T_N;   // [275][275] (u-major, t contig)
    const int tid = threadIdx.x;
    const int tx = tid & 15, ty = tid >> 4;
    float acc[4][4] = {};

    for (int t0 = 0; t0 < T_N; t0 += TK) {
        #pragma unroll
        for (int l = tid; l < 64 * TK; l += 256) {
            int r  = l >> 4;        // 0..63
            int tt = l & 15;
            int t  = t0 + tt;
            As[tt][r] = (t < T_N) ? A[r * T_N + t] : 0.0f;
            int u = u0 + r;
            Bs[tt][r] = (u < T_N && t < T_N) ? W[u * T_N + t] : 0.0f;
        }
        __syncthreads();
        #pragma unroll
        for (int tt = 0; tt < TK; ++tt) {
            float a[4], bv[4];
            #pragma unroll
            for (int i = 0; i < 4; ++i) a[i]  = As[tt][ty * 4 + i];
            #pragma unroll
            for (int j = 0; j < 4; ++j) bv[j] = Bs[tt][tx * 4 + j];
            #pragma unroll
            for (int i = 0; i < 4; ++i)
                #pragma unroll
                for (int j = 0; j < 4; ++j)
                    acc[i][j] += a[i] * bv[j];
        }
        __syncthreads();
    }

    #pragma unroll
    for (int i = 0; i < 4; ++i) {
        int c = ty * 4 + i;
        #pragma unroll
        for (int j = 0; j < 4; ++j) {
            int u = u0 + tx * 4 + j;
            if (u < T_N)
                x[(size_t)b * CT_N + c * T_N + u] = acc[i][j] + subj_b[s * T_N + u];
        }
    }
}

// ---------------------------------------------------------------------------
// K2: partial[z,m,n] = sum_{k in chunk z} x[m,k] * encW[k,n]
// grid: (16 m-tiles, 3 n-tiles, KSPLIT), block 256
// ---------------------------------------------------------------------------
__global__ __launch_bounds__(256) void k2_enc_gemm(
    const float* __restrict__ x, const float* __restrict__ encW,
    float* __restrict__ partial)
{
    __shared__ float As[TK][68];
    __shared__ float Bs[TK][68];
    const int m0 = blockIdx.x * 64;
    const int n0 = blockIdx.y * 64;
    const int kz = blockIdx.z;
    const int kbeg = kz * KCHUNK, kend = kbeg + KCHUNK;
    const int tid = threadIdx.x;
    const int tx = tid & 15, ty = tid >> 4;
    float acc[4][4] = {};

    for (int k0 = kbeg; k0 < kend; k0 += TK) {
        #pragma unroll
        for (int l = tid; l < 64 * TK; l += 256) {
            int mm = l >> 4, tt = l & 15;
            int k = k0 + tt;
            As[tt][mm] = (k < kend) ? x[(size_t)(m0 + mm) * CT_N + k] : 0.0f;
        }
        #pragma unroll
        for (int l = tid; l < 64 * TK; l += 256) {
            int tt = l >> 6, nn = l & 63;
            int k = k0 + tt;
            int n = n0 + nn;
            Bs[tt][nn] = (k < kend && n < EMB_N) ? encW[(size_t)k * EMB_N + n] : 0.0f;
        }
        __syncthreads();
        #pragma unroll
        for (int tt = 0; tt < TK; ++tt) {
            float a[4], bv[4];
            #pragma unroll
            for (int i = 0; i < 4; ++i) a[i]  = As[tt][ty * 4 + i];
            #pragma unroll
            for (int j = 0; j < 4; ++j) bv[j] = Bs[tt][tx * 4 + j];
            #pragma unroll
            for (int i = 0; i < 4; ++i)
                #pragma unroll
                for (int j = 0; j < 4; ++j)
                    acc[i][j] += a[i] * bv[j];
        }
        __syncthreads();
    }

    #pragma unroll
    for (int i = 0; i < 4; ++i) {
        int m = m0 + ty * 4 + i;
        #pragma unroll
        for (int j = 0; j < 4; ++j) {
            int n = n0 + tx * 4 + j;
            if (n < EMB_N)
                partial[((size_t)kz * B_N + m) * EMB_N + n] = acc[i][j];
        }
    }
}

// ---------------------------------------------------------------------------
// K3: h[m,n] = enc_b[n] + sum_z partial[z,m,n]
// ---------------------------------------------------------------------------
__global__ __launch_bounds__(256) void k3_enc_reduce(
    const float* __restrict__ partial, const float* __restrict__ enc_b,
    float* __restrict__ h)
{
    int idx = blockIdx.x * 256 + threadIdx.x;
    if (idx >= B_N * EMB_N) return;
    int n = idx % EMB_N;
    float s = enc_b[n];
    #pragma unroll
    for (int z = 0; z < KSPLIT; ++z)
        s += partial[(size_t)z * B_N * EMB_N + idx];
    h[idx] = s;
}

// ---------------------------------------------------------------------------
// K4: h1 = h @ W1 + b1   (M=1024, K=184, N=1024)
// grid (16,16), block 256
// ---------------------------------------------------------------------------
__global__ __launch_bounds__(256) void k4_proj1(
    const float* __restrict__ h, const float* __restrict__ W1,
    const float* __restrict__ b1, float* __restrict__ h1)
{
    __shared__ float As[TK][68];
    __shared__ float Bs[TK][68];
    const int m0 = blockIdx.x * 64;
    const int n0 = blockIdx.y * 64;
    const int tid = threadIdx.x;
    const int tx = tid & 15, ty = tid >> 4;
    float acc[4][4] = {};

    for (int k0 = 0; k0 < EMB_N; k0 += TK) {
        #pragma unroll
        for (int l = tid; l < 64 * TK; l += 256) {
            int mm = l >> 4, tt = l & 15;
            int k = k0 + tt;
            As[tt][mm] = (k < EMB_N) ? h[(size_t)(m0 + mm) * EMB_N + k] : 0.0f;
        }
        #pragma unroll
        for (int l = tid; l < 64 * TK; l += 256) {
            int tt = l >> 6, nn = l & 63;
            int k = k0 + tt;
            Bs[tt][nn] = (k < EMB_N) ? W1[(size_t)k * PROJ_N + n0 + nn] : 0.0f;
        }
        __syncthreads();
        #pragma unroll
        for (int tt = 0; tt < TK; ++tt) {
            float a[4], bv[4];
            #pragma unroll
            for (int i = 0; i < 4; ++i) a[i]  = As[tt][ty * 4 + i];
            #pragma unroll
            for (int j = 0; j < 4; ++j) bv[j] = Bs[tt][tx * 4 + j];
            #pragma unroll
            for (int i = 0; i < 4; ++i)
                #pragma unroll
                for (int j = 0; j < 4; ++j)
                    acc[i][j] += a[i] * bv[j];
        }
        __syncthreads();
    }

    #pragma unroll
    for (int i = 0; i < 4; ++i) {
        int m = m0 + ty * 4 + i;
        #pragma unroll
        for (int j = 0; j < 4; ++j) {
            int n = n0 + tx * 4 + j;
            h1[(size_t)m * PROJ_N + n] = acc[i][j] + b1[n];
        }
    }
}

// ---------------------------------------------------------------------------
// K5: hr = h1 + (gelu(h1) @ W2 + b2)   (M=N=K=1024)
// grid (16,16), block 256
// ---------------------------------------------------------------------------
__global__ __launch_bounds__(256) void k5_proj2(
    const float* __restrict__ h1, const float* __restrict__ W2,
    const float* __restrict__ b2, float* __restrict__ hr)
{
    __shared__ float As[TK][68];
    __shared__ float Bs[TK][68];
    const int m0 = blockIdx.x * 64;
    const int n0 = blockIdx.y * 64;
    const int tid = threadIdx.x;
    const int tx = tid & 15, ty = tid >> 4;
    float acc[4][4] = {};

    for (int k0 = 0; k0 < PROJ_N; k0 += TK) {
        #pragma unroll
        for (int l = tid; l < 64 * TK; l += 256) {
            int mm = l >> 4, tt = l & 15;
            int k = k0 + tt;
            As[tt][mm] = gelu_exact(h1[(size_t)(m0 + mm) * PROJ_N + k]);
        }
        #pragma unroll
        for (int l = tid; l < 64 * TK; l += 256) {
            int tt = l >> 6, nn = l & 63;
            int k = k0 + tt;
            Bs[tt][nn] = W2[(size_t)k * PROJ_N + n0 + nn];
        }
        __syncthreads();
        #pragma unroll
        for (int tt = 0; tt < TK; ++tt) {
            float a[4], bv[4];
            #pragma unroll
            for (int i = 0; i < 4; ++i) a[i]  = As[tt][ty * 4 + i];
            #pragma unroll
            for (int j = 0; j < 4; ++j) bv[j] = Bs[tt][tx * 4 + j];
            #pragma unroll
            for (int i = 0; i < 4; ++i)
                #pragma unroll
                for (int j = 0; j < 4; ++j)
                    acc[i][j] += a[i] * bv[j];
        }
        __syncthreads();
    }

    #pragma unroll
    for (int i = 0; i < 4; ++i) {
        int m = m0 + ty * 4 + i;
        #pragma unroll
        for (int j = 0; j < 4; ++j) {
            int n = n0 + tx * 4 + j;
            size_t o = (size_t)m * PROJ_N + n;
            hr[o] = h1[o] + acc[i][j] + b2[n];
        }
    }
}

// ---------------------------------------------------------------------------
// K6: out = LayerNorm(hr) * gamma + beta, per row of 1024
// grid (1024), block 256
// ---------------------------------------------------------------------------
__global__ __launch_bounds__(256) void k6_layernorm(
    const float* __restrict__ hr, const float* __restrict__ gamma,
    const float* __restrict__ beta, float* __restrict__ out)
{
    const int row = blockIdx.x;
    const int tid = threadIdx.x;
    const float* r = hr + (size_t)row * PROJ_N;
    float v[4];
    float s = 0.f, sq = 0.f;
    #pragma unroll
    for (int i = 0; i < 4; ++i) {
        v[i] = r[tid + i * 256];
        s  += v[i];
        sq += v[i] * v[i];
    }
    #pragma unroll
    for (int off = 32; off > 0; off >>= 1) {
        s  += __shfl_down(s, off);
        sq += __shfl_down(sq, off);
    }
    __shared__ float ss[4], ssq[4];
    int wid = tid >> 6, lane = tid & 63;
    if (lane == 0) { ss[wid] = s; ssq[wid] = sq; }
    __syncthreads();
    if (tid == 0) {
        float a = 0.f, bsum = 0.f;
        #pragma unroll
        for (int w = 0; w < 4; ++w) { a += ss[w]; bsum += ssq[w]; }
        ss[0] = a; ssq[0] = bsum;
    }
    __syncthreads();
    float mu  = ss[0] * (1.0f / PROJ_N);
    float var = ssq[0] * (1.0f / PROJ_N) - mu * mu;
    float rs  = rsqrtf(var + 1e-5f);
    #pragma unroll
    for (int i = 0; i < 4; ++i) {
        int n = tid + i * 256;
        out[(size_t)row * PROJ_N + n] = (v[i] - mu) * rs * gamma[n] + beta[n];
    }
}

// ---------------------------------------------------------------------------
extern "C" void kernel_launch(void* const* d_in, const int* in_sizes, int n_in,
                              void* d_out, int out_size, void* d_ws, size_t ws_size,
                              hipStream_t stream)
{
    const float* eeg    = (const float*)d_in[0];
    const int*   sid    = (const int*)  d_in[1];
    const float* subj_W = (const float*)d_in[2];
    const float* subj_b = (const float*)d_in[3];
    const float* enc_W  = (const float*)d_in[4];
    const float* enc_b  = (const float*)d_in[5];
    const float* W1     = (const float*)d_in[6];
    const float* b1     = (const float*)d_in[7];
    const float* W2     = (const float*)d_in[8];
    const float* b2     = (const float*)d_in[9];
    const float* gamma  = (const float*)d_in[10];
    const float* beta   = (const float*)d_in[11];
    float* out = (float*)d_out;

    float* x       = (float*)d_ws;                          // B*C*T        = 18,022,400
    float* partial = x + (size_t)B_N * CT_N;                // KSPLIT*B*EMB =  3,014,656
    float* h       = partial + (size_t)KSPLIT * B_N * EMB_N;// B*EMB        =    188,416
    float* h1      = h + (size_t)B_N * EMB_N;               // B*PROJ       =  1,048,576
    float* hr      = h1 + (size_t)B_N * PROJ_N;             // B*PROJ       =  1,048,576

    k1_subj_align<<<dim3(5, B_N), 256, 0, stream>>>(eeg, sid, subj_W, subj_b, x);
    k2_enc_gemm<<<dim3(16, 3, KSPLIT), 256, 0, stream>>>(x, enc_W, partial);
    k3_enc_reduce<<<dim3((B_N * EMB_N + 255) / 256), 256, 0, stream>>>(partial, enc_b, h);
    k4_proj1<<<dim3(16, 16), 256, 0, stream>>>(h, W1, b1, h1);
    k5_proj2<<<dim3(16, 16), 256, 0, stream>>>(h1, W2, b2, hr);
    k6_layernorm<<<dim3(B_N), 256, 0, stream>>>(hr, gamma, beta, out);
}

// Round 2
// 161.453 us; speedup vs baseline: 4.1622x; 4.1622x over previous
//
#include <hip/hip_runtime.h>
#include <math.h>

#define B_N    1024
#define C_N    64
#define T_N    275
#define S_N    10
#define EMB_N  184
#define PROJ_N 1024
#define CT_N   (C_N * T_N)      // 17600
#define TP     288              // padded T (9*32)
#define KP     (C_N * TP)       // 18432
#define EMBP   192              // padded EMB
#define KSPLIT 16
#define KCH    (KP / KSPLIT)    // 1152

typedef unsigned short u16;
typedef __attribute__((ext_vector_type(8))) short short8;
typedef __attribute__((ext_vector_type(4))) float f32x4;

#define MFMA16(a,b,c) __builtin_amdgcn_mfma_f32_16x16x32_bf16(a, b, c, 0, 0, 0)

__device__ __forceinline__ u16 f2bf(float f) {
    union { float f; unsigned u; } v; v.f = f;
    unsigned r = v.u + 0x7FFFu + ((v.u >> 16) & 1u);   // RNE
    return (u16)(r >> 16);
}
__device__ __forceinline__ float gelu_exact(float v) {
    return 0.5f * v * (1.0f + erff(v * 0.70710678118654752f));
}

// ---------------------------------------------------------------------------
// Prep: subj_W f32 [10][275][275] -> bf16 [10][275][288] (t zero-padded)
// ---------------------------------------------------------------------------
__global__ __launch_bounds__(256) void p_wbf16(const float* __restrict__ W,
                                               u16* __restrict__ Wb)
{
    int idx = blockIdx.x * 256 + threadIdx.x;
    if (idx >= S_N * T_N * TP) return;
    int row = idx / TP;          // s*275+u
    int t   = idx - row * TP;
    Wb[idx] = (t < T_N) ? f2bf(W[(size_t)row * T_N + t]) : (u16)0;
}

// ---------------------------------------------------------------------------
// Prep: enc_W f32 [17600][184] -> encWT bf16 [192][18432] (transposed, padded)
//   k' = c*288+t maps to source row c*275+t (zero if t>=275 or n>=184)
// ---------------------------------------------------------------------------
__global__ __launch_bounds__(256) void p_encwt(const float* __restrict__ encW,
                                               u16* __restrict__ eT)
{
    __shared__ float tile[64][65];
    const int k0 = blockIdx.x * 64, n0 = blockIdx.y * 64;
    for (int l = threadIdx.x; l < 4096; l += 256) {
        int i = l >> 6, j = l & 63;
        int kk = k0 + i;
        int c = kk / TP, t = kk - c * TP;
        int n = n0 + j;
        float v = 0.f;
        if (t < T_N && n < EMB_N) v = encW[((size_t)c * T_N + t) * EMB_N + n];
        tile[i][j] = v;
    }
    __syncthreads();
    for (int l = threadIdx.x; l < 4096; l += 256) {
        int j = l >> 6, i = l & 63;
        eT[(size_t)(n0 + j) * KP + k0 + i] = f2bf(tile[i][j]);
    }
}

// ---------------------------------------------------------------------------
// Prep: W1 f32 [184][1024] -> W1T bf16 [1024][192] (k zero-padded)
// ---------------------------------------------------------------------------
__global__ __launch_bounds__(256) void p_w1t(const float* __restrict__ W1,
                                             u16* __restrict__ w1t)
{
    __shared__ float tile[64][65];
    const int k0 = blockIdx.x * 64, n0 = blockIdx.y * 64;
    for (int l = threadIdx.x; l < 4096; l += 256) {
        int i = l >> 6, j = l & 63;
        float v = (k0 + i < EMB_N) ? W1[(size_t)(k0 + i) * PROJ_N + n0 + j] : 0.f;
        tile[i][j] = v;
    }
    __syncthreads();
    for (int l = threadIdx.x; l < 4096; l += 256) {
        int j = l >> 6, i = l & 63;
        w1t[(size_t)(n0 + j) * EMBP + k0 + i] = f2bf(tile[i][j]);
    }
}

// ---------------------------------------------------------------------------
// Prep: W2 f32 [1024][1024] -> W2T bf16 [1024][1024]
// ---------------------------------------------------------------------------
__global__ __launch_bounds__(256) void p_w2t(const float* __restrict__ W2,
                                             u16* __restrict__ w2t)
{
    __shared__ float tile[64][65];
    const int k0 = blockIdx.x * 64, n0 = blockIdx.y * 64;
    for (int l = threadIdx.x; l < 4096; l += 256) {
        int i = l >> 6, j = l & 63;
        tile[i][j] = W2[(size_t)(k0 + i) * PROJ_N + n0 + j];
    }
    __syncthreads();
    for (int l = threadIdx.x; l < 4096; l += 256) {
        int j = l >> 6, i = l & 63;
        w2t[(size_t)(n0 + j) * PROJ_N + k0 + i] = f2bf(tile[i][j]);
    }
}

// ---------------------------------------------------------------------------
// K1: x[b,c,u] = sum_t eeg[b,c,t]*W[s,u,t] + bias[s,u]  (MFMA bf16)
// one block per b; out xb bf16 [B][64][288] (u>=275 zeroed)
// ---------------------------------------------------------------------------
#define A_STRIDE 296   // bf16 units; 592B: 16B-aligned, uniform banks
#define B_STRIDE 40    // bf16 units; 80B: 16B-aligned, uniform banks

__global__ __launch_bounds__(256, 2) void k1_mfma(
    const float* __restrict__ eeg, const int* __restrict__ sid,
    const u16* __restrict__ Wb, const float* __restrict__ subj_b,
    u16* __restrict__ xb)
{
    __shared__ u16 As[64 * A_STRIDE];   // [c][t], full K
    __shared__ u16 Bs[TP * B_STRIDE];   // [u][32-chunk of t]
    const int b   = blockIdx.x;
    const int s   = sid[b];
    const int tid = threadIdx.x;
    const int w = tid >> 6, lane = tid & 63;
    const int wr = w >> 1, wc = w & 1;          // 2x2 waves: 32 rows x 144 cols
    const int lrow = lane & 15, lk = lane >> 4; // fragment coords

    // stage A: eeg[b] 64x275 f32 -> bf16 LDS (flat float4 reads, 16B-aligned)
    const float4* A4 = reinterpret_cast<const float4*>(eeg + (size_t)b * CT_N);
    for (int l = tid; l < CT_N / 4; l += 256) {
        float4 v = A4[l];
        float vv[4] = { v.x, v.y, v.z, v.w };
        int base = l * 4;
        #pragma unroll
        for (int e = 0; e < 4; ++e) {
            int idx = base + e;
            int c = idx / T_N, t = idx - c * T_N;
            As[c * A_STRIDE + t] = f2bf(vv[e]);
        }
    }
    for (int l = tid; l < 64 * (TP - T_N); l += 256) {      // zero t pad 275..287
        int c = l / (TP - T_N), t = T_N + (l - c * (TP - T_N));
        As[c * A_STRIDE + t] = 0;
    }

    const u16* Wrow = Wb + (size_t)s * T_N * TP;
    f32x4 acc[2][9] = {};

    for (int ks = 0; ks < TP / 32; ++ks) {
        const int t0 = ks * 32;
        // stage B: W[u][t0..t0+31] bf16, 275 rows x 4 x 16B
        for (int l = tid; l < T_N * 4; l += 256) {
            int u = l >> 2, q = l & 3;
            *reinterpret_cast<uint4*>(&Bs[u * B_STRIDE + q * 8]) =
                *reinterpret_cast<const uint4*>(&Wrow[(size_t)u * TP + t0 + q * 8]);
        }
        __syncthreads();
        short8 af[2];
        af[0] = *reinterpret_cast<const short8*>(&As[(32 * wr + lrow) * A_STRIDE + t0 + 8 * lk]);
        af[1] = *reinterpret_cast<const short8*>(&As[(32 * wr + 16 + lrow) * A_STRIDE + t0 + 8 * lk]);
        #pragma unroll
        for (int ct = 0; ct < 9; ++ct) {
            int u = 144 * wc + 16 * ct + lrow;
            short8 bf = *reinterpret_cast<const short8*>(&Bs[u * B_STRIDE + 8 * lk]);
            acc[0][ct] = MFMA16(af[0], bf, acc[0][ct]);
            acc[1][ct] = MFMA16(af[1], bf, acc[1][ct]);
        }
        __syncthreads();
    }

    // epilogue: +bias, store bf16 (u>=275 -> 0, keeps K-pads clean for k2)
    #pragma unroll
    for (int ct = 0; ct < 9; ++ct) {
        int u = 144 * wc + 16 * ct + lrow;
        float bias = (u < T_N) ? subj_b[s * T_N + u] : 0.f;
        #pragma unroll
        for (int rt = 0; rt < 2; ++rt) {
            int c = 32 * wr + 16 * rt + 4 * lk;
            size_t base = (size_t)b * KP + (size_t)c * TP + u;
            #pragma unroll
            for (int r = 0; r < 4; ++r) {
                float v = (u < T_N) ? (acc[rt][ct][r] + bias) : 0.f;
                xb[base + (size_t)r * TP] = f2bf(v);
            }
        }
    }
}

// ---------------------------------------------------------------------------
// K2: partial[kz,m,n] = sum_{k in chunk} xb[m,k]*encWT[n,k]   (MFMA)
// grid (16 m-tiles, 16 kz)
// ---------------------------------------------------------------------------
__global__ __launch_bounds__(256) void k2_mfma(
    const u16* __restrict__ xb, const u16* __restrict__ eT,
    float* __restrict__ part)
{
    __shared__ u16 As[64 * B_STRIDE];
    __shared__ u16 Bs[EMBP * B_STRIDE];
    const int m0 = blockIdx.x * 64;
    const int kz = blockIdx.y;
    const int tid = threadIdx.x;
    const int w = tid >> 6, lane = tid & 63;
    const int wr = w >> 1, wc = w & 1;          // 32 rows x 96 cols per wave
    const int lrow = lane & 15, lk = lane >> 4;
    f32x4 acc[2][6] = {};

    for (int ks = 0; ks < KCH / 32; ++ks) {
        const int k0 = kz * KCH + ks * 32;
        { int u = tid >> 2, q = tid & 3;
          *reinterpret_cast<uint4*>(&As[u * B_STRIDE + q * 8]) =
              *reinterpret_cast<const uint4*>(&xb[(size_t)(m0 + u) * KP + k0 + q * 8]); }
        for (int l = tid; l < EMBP * 4; l += 256) {
            int u = l >> 2, q = l & 3;
            *reinterpret_cast<uint4*>(&Bs[u * B_STRIDE + q * 8]) =
                *reinterpret_cast<const uint4*>(&eT[(size_t)u * KP + k0 + q * 8]);
        }
        __syncthreads();
        short8 af[2];
        af[0] = *reinterpret_cast<const short8*>(&As[(32 * wr + lrow) * B_STRIDE + 8 * lk]);
        af[1] = *reinterpret_cast<const short8*>(&As[(32 * wr + 16 + lrow) * B_STRIDE + 8 * lk]);
        #pragma unroll
        for (int ct = 0; ct < 6; ++ct) {
            short8 bf = *reinterpret_cast<const short8*>(&Bs[(96 * wc + 16 * ct + lrow) * B_STRIDE + 8 * lk]);
            acc[0][ct] = MFMA16(af[0], bf, acc[0][ct]);
            acc[1][ct] = MFMA16(af[1], bf, acc[1][ct]);
        }
        __syncthreads();
    }
    #pragma unroll
    for (int rt = 0; rt < 2; ++rt) {
        int mb = m0 + 32 * wr + 16 * rt + 4 * lk;
        #pragma unroll
        for (int ct = 0; ct < 6; ++ct) {
            int n = 96 * wc + 16 * ct + lrow;
            #pragma unroll
            for (int r = 0; r < 4; ++r)
                part[((size_t)kz * B_N + mb + r) * EMBP + n] = acc[rt][ct][r];
        }
    }
}

// ---------------------------------------------------------------------------
// K3: hb[m,n] = bf16(enc_b[n] + sum_z partial[z,m,n]); n>=184 -> 0
// ---------------------------------------------------------------------------
__global__ __launch_bounds__(256) void k3_reduce(
    const float* __restrict__ part, const float* __restrict__ enc_b,
    u16* __restrict__ hb)
{
    int idx = blockIdx.x * 256 + threadIdx.x;
    if (idx >= B_N * EMBP) return;
    int n = idx % EMBP, m = idx / EMBP;
    float s = 0.f;
    if (n < EMB_N) {
        s = enc_b[n];
        #pragma unroll
        for (int z = 0; z < KSPLIT; ++z)
            s += part[((size_t)z * B_N + m) * EMBP + n];
    }
    hb[idx] = f2bf(s);
}

// ---------------------------------------------------------------------------
// K4: h1 = hb @ W1T^T + b1 ; g = bf16(gelu(h1))   (MFMA, K=192)
// grid (16,16)
// ---------------------------------------------------------------------------
__global__ __launch_bounds__(256) void k4_mfma(
    const u16* __restrict__ hb, const u16* __restrict__ w1t,
    const float* __restrict__ b1, float* __restrict__ h1, u16* __restrict__ g)
{
    __shared__ u16 As[64 * B_STRIDE];
    __shared__ u16 Bs[64 * B_STRIDE];
    const int m0 = blockIdx.x * 64, n0 = blockIdx.y * 64;
    const int tid = threadIdx.x;
    const int w = tid >> 6, lane = tid & 63;
    const int wr = w >> 1, wc = w & 1;          // 32x32 per wave
    const int lrow = lane & 15, lk = lane >> 4;
    f32x4 acc[2][2] = {};

    for (int ks = 0; ks < EMBP / 32; ++ks) {
        const int k0 = ks * 32;
        int u = tid >> 2, q = tid & 3;
        *reinterpret_cast<uint4*>(&As[u * B_STRIDE + q * 8]) =
            *reinterpret_cast<const uint4*>(&hb[(size_t)(m0 + u) * EMBP + k0 + q * 8]);
        *reinterpret_cast<uint4*>(&Bs[u * B_STRIDE + q * 8]) =
            *reinterpret_cast<const uint4*>(&w1t[(size_t)(n0 + u) * EMBP + k0 + q * 8]);
        __syncthreads();
        #pragma unroll
        for (int rt = 0; rt < 2; ++rt) {
            short8 af = *reinterpret_cast<const short8*>(&As[(32 * wr + 16 * rt + lrow) * B_STRIDE + 8 * lk]);
            #pragma unroll
            for (int ct = 0; ct < 2; ++ct) {
                short8 bf = *reinterpret_cast<const short8*>(&Bs[(32 * wc + 16 * ct + lrow) * B_STRIDE + 8 * lk]);
                acc[rt][ct] = MFMA16(af, bf, acc[rt][ct]);
            }
        }
        __syncthreads();
    }
    #pragma unroll
    for (int rt = 0; rt < 2; ++rt)
        #pragma unroll
        for (int ct = 0; ct < 2; ++ct) {
            int n = n0 + 32 * wc + 16 * ct + lrow;
            #pragma unroll
            for (int r = 0; r < 4; ++r) {
                int m = m0 + 32 * wr + 16 * rt + 4 * lk + r;
                float v = acc[rt][ct][r] + b1[n];
                size_t o = (size_t)m * PROJ_N + n;
                h1[o] = v;
                g[o]  = f2bf(gelu_exact(v));
            }
        }
}

// ---------------------------------------------------------------------------
// K5: hr = h1 + g @ W2T^T + b2   (MFMA, K=1024)
// grid (16,16)
// ---------------------------------------------------------------------------
__global__ __launch_bounds__(256) void k5_mfma(
    const u16* __restrict__ g, const u16* __restrict__ w2t,
    const float* __restrict__ h1, const float* __restrict__ b2,
    float* __restrict__ hr)
{
    __shared__ u16 As[64 * B_STRIDE];
    __shared__ u16 Bs[64 * B_STRIDE];
    const int m0 = blockIdx.x * 64, n0 = blockIdx.y * 64;
    const int tid = threadIdx.x;
    const int w = tid >> 6, lane = tid & 63;
    const int wr = w >> 1, wc = w & 1;
    const int lrow = lane & 15, lk = lane >> 4;
    f32x4 acc[2][2] = {};

    for (int ks = 0; ks < PROJ_N / 32; ++ks) {
        const int k0 = ks * 32;
        int u = tid >> 2, q = tid & 3;
        *reinterpret_cast<uint4*>(&As[u * B_STRIDE + q * 8]) =
            *reinterpret_cast<const uint4*>(&g[(size_t)(m0 + u) * PROJ_N + k0 + q * 8]);
        *reinterpret_cast<uint4*>(&Bs[u * B_STRIDE + q * 8]) =
            *reinterpret_cast<const uint4*>(&w2t[(size_t)(n0 + u) * PROJ_N + k0 + q * 8]);
        __syncthreads();
        #pragma unroll
        for (int rt = 0; rt < 2; ++rt) {
            short8 af = *reinterpret_cast<const short8*>(&As[(32 * wr + 16 * rt + lrow) * B_STRIDE + 8 * lk]);
            #pragma unroll
            for (int ct = 0; ct < 2; ++ct) {
                short8 bf = *reinterpret_cast<const short8*>(&Bs[(32 * wc + 16 * ct + lrow) * B_STRIDE + 8 * lk]);
                acc[rt][ct] = MFMA16(af, bf, acc[rt][ct]);
            }
        }
        __syncthreads();
    }
    #pragma unroll
    for (int rt = 0; rt < 2; ++rt)
        #pragma unroll
        for (int ct = 0; ct < 2; ++ct) {
            int n = n0 + 32 * wc + 16 * ct + lrow;
            #pragma unroll
            for (int r = 0; r < 4; ++r) {
                int m = m0 + 32 * wr + 16 * rt + 4 * lk + r;
                size_t o = (size_t)m * PROJ_N + n;
                hr[o] = h1[o] + acc[rt][ct][r] + b2[n];
            }
        }
}

// ---------------------------------------------------------------------------
// K6: out = LayerNorm(hr)*gamma + beta
// ---------------------------------------------------------------------------
__global__ __launch_bounds__(256) void k6_layernorm(
    const float* __restrict__ hr, const float* __restrict__ gamma,
    const float* __restrict__ beta, float* __restrict__ out)
{
    const int row = blockIdx.x;
    const int tid = threadIdx.x;
    const float* r = hr + (size_t)row * PROJ_N;
    float v[4];
    float s = 0.f, sq = 0.f;
    #pragma unroll
    for (int i = 0; i < 4; ++i) {
        v[i] = r[tid + i * 256];
        s  += v[i];
        sq += v[i] * v[i];
    }
    #pragma unroll
    for (int off = 32; off > 0; off >>= 1) {
        s  += __shfl_down(s, off);
        sq += __shfl_down(sq, off);
    }
    __shared__ float ss[4], ssq[4];
    int wid = tid >> 6, lane = tid & 63;
    if (lane == 0) { ss[wid] = s; ssq[wid] = sq; }
    __syncthreads();
    if (tid == 0) {
        float a = 0.f, bsum = 0.f;
        #pragma unroll
        for (int w = 0; w < 4; ++w) { a += ss[w]; bsum += ssq[w]; }
        ss[0] = a; ssq[0] = bsum;
    }
    __syncthreads();
    float mu  = ss[0] * (1.0f / PROJ_N);
    float var = ssq[0] * (1.0f / PROJ_N) - mu * mu;
    float rs  = rsqrtf(var + 1e-5f);
    #pragma unroll
    for (int i = 0; i < 4; ++i) {
        int n = tid + i * 256;
        out[(size_t)row * PROJ_N + n] = (v[i] - mu) * rs * gamma[n] + beta[n];
    }
}

// ---------------------------------------------------------------------------
extern "C" void kernel_launch(void* const* d_in, const int* in_sizes, int n_in,
                              void* d_out, int out_size, void* d_ws, size_t ws_size,
                              hipStream_t stream)
{
    const float* eeg    = (const float*)d_in[0];
    const int*   sid    = (const int*)  d_in[1];
    const float* subj_W = (const float*)d_in[2];
    const float* subj_b = (const float*)d_in[3];
    const float* enc_W  = (const float*)d_in[4];
    const float* enc_b  = (const float*)d_in[5];
    const float* W1     = (const float*)d_in[6];
    const float* b1     = (const float*)d_in[7];
    const float* W2     = (const float*)d_in[8];
    const float* b2     = (const float*)d_in[9];
    const float* gamma  = (const float*)d_in[10];
    const float* beta   = (const float*)d_in[11];
    float* out = (float*)d_out;

    char* w = (char*)d_ws;
    u16*   xb   = (u16*)  (w);              // 1024*18432*2 = 37,748,736
    u16*   Wb   = (u16*)  (w + 37748736);   //  1,584,128 (10*275*288*2 padded)
    u16*   eT   = (u16*)  (w + 39332864);   //  7,077,888 (192*18432*2)
    u16*   w1t  = (u16*)  (w + 46410752);   //    393,216 (1024*192*2)
    u16*   w2t  = (u16*)  (w + 46803968);   //  2,097,152 (1024*1024*2)
    float* part = (float*)(w + 48901120);   // 12,582,912 (16*1024*192*4)
    u16*   hb   = (u16*)  (w + 61484032);   //    393,216 (1024*192*2)
    float* h1   = (float*)(w + 61877248);   //  4,194,304
    u16*   g    = (u16*)  (w + 66071552);   //  2,097,152
    float* hr   = (float*)(w + 68168704);   //  4,194,304  -> total 72,363,008 B

    p_wbf16<<<dim3((S_N * T_N * TP + 255) / 256), 256, 0, stream>>>(subj_W, Wb);
    p_encwt<<<dim3(KP / 64, EMBP / 64), 256, 0, stream>>>(enc_W, eT);
    p_w1t  <<<dim3(EMBP / 64, PROJ_N / 64), 256, 0, stream>>>(W1, w1t);
    p_w2t  <<<dim3(PROJ_N / 64, PROJ_N / 64), 256, 0, stream>>>(W2, w2t);

    k1_mfma<<<dim3(B_N), 256, 0, stream>>>(eeg, sid, Wb, subj_b, xb);
    k2_mfma<<<dim3(B_N / 64, KSPLIT), 256, 0, stream>>>(xb, eT, part);
    k3_reduce<<<dim3((B_N * EMBP + 255) / 256), 256, 0, stream>>>(part, enc_b, hb);
    k4_mfma<<<dim3(B_N / 64, PROJ_N / 64), 256, 0, stream>>>(hb, w1t, b1, h1, g);
    k5_mfma<<<dim3(B_N / 64, PROJ_N / 64), 256, 0, stream>>>(g, w2t, h1, b2, hr);
    k6_layernorm<<<dim3(B_N), 256, 0, stream>>>(hr, gamma, beta, out);
}

// Round 3
// 143.181 us; speedup vs baseline: 4.6934x; 1.1276x over previous
//
#include <hip/hip_runtime.h>
#include <math.h>

#define B_N    1024
#define C_N    64
#define T_N    275
#define S_N    10
#define EMB_N  184
#define PROJ_N 1024
#define CT_N   (C_N * T_N)      // 17600
#define TP     288              // K extent for k1 (9*32), u extent padded
#define TPAD   296              // row stride (bf16) for eegb/Wb: 592B, 16B-mult
#define KP2    18432            // k2 K dim = 288*64
#define EMBP   192
#define KZ2    32
#define KC2    (KP2 / KZ2)      // 576
#define KZ5    2

typedef unsigned short u16;
typedef __attribute__((ext_vector_type(8))) short short8;
typedef __attribute__((ext_vector_type(4))) short short4v;
typedef __attribute__((ext_vector_type(4))) float f32x4;

#define MFMA16(a,b,c) __builtin_amdgcn_mfma_f32_16x16x32_bf16(a, b, c, 0, 0, 0)

__device__ __forceinline__ u16 f2bf(float f) {
    union { float f; unsigned u; } v; v.f = f;
    unsigned r = v.u + 0x7FFFu + ((v.u >> 16) & 1u);   // RNE
    return (u16)(r >> 16);
}
__device__ __forceinline__ float gelu_exact(float v) {
    return 0.5f * v * (1.0f + erff(v * 0.70710678118654752f));
}
__device__ __forceinline__ void gload16(const void* g, void* lds) {
    __builtin_amdgcn_global_load_lds(
        (const __attribute__((address_space(1))) void*)g,
        (__attribute__((address_space(3))) void*)lds, 16, 0, 0);
}

// ---------------------------------------------------------------------------
// p_eeg: eeg f32 [B][64][275] -> eegb bf16 [B][64][296] (t>=275 zero)
// ---------------------------------------------------------------------------
__global__ __launch_bounds__(256) void p_eeg(const float* __restrict__ eeg,
                                             u16* __restrict__ eegb)
{
    const int b = blockIdx.x;
    const float* src = eeg + (size_t)b * CT_N;
    u16* dst = eegb + (size_t)b * C_N * TPAD;
    for (int o4 = threadIdx.x; o4 < C_N * TPAD / 4; o4 += 256) {
        int o = o4 * 4;
        int r = o / TPAD, tt = o - r * TPAD;
        short4v pk;
        #pragma unroll
        for (int e = 0; e < 4; ++e) {
            int t = tt + e;
            float v = (t < T_N) ? src[r * T_N + t] : 0.f;
            pk[e] = (short)f2bf(v);
        }
        *reinterpret_cast<short4v*>(dst + o) = pk;
    }
}

// ---------------------------------------------------------------------------
// p_wbf16: subj_W f32 [10][275][275] -> Wb bf16 [10][288][296] (u,t pads zero)
// ---------------------------------------------------------------------------
__global__ __launch_bounds__(256) void p_wbf16(const float* __restrict__ W,
                                               u16* __restrict__ Wb)
{
    int idx4 = blockIdx.x * 256 + threadIdx.x;
    if (idx4 >= S_N * TP * TPAD / 4) return;
    int o = idx4 * 4;
    int row = o / TPAD, tt = o - row * TPAD;   // row = s*288 + u
    int s = row / TP, u = row - s * TP;
    short4v pk;
    #pragma unroll
    for (int e = 0; e < 4; ++e) {
        int t = tt + e;
        float v = (u < T_N && t < T_N) ? W[((size_t)s * T_N + u) * T_N + t] : 0.f;
        pk[e] = (short)f2bf(v);
    }
    *reinterpret_cast<short4v*>(Wb + o) = pk;
}

// ---------------------------------------------------------------------------
// p_encwt: enc_W f32 [17600=c*275+t][184] -> eT bf16 [192][18432 = t*64+c]
// grid (288 t, 3 n-tiles)
// ---------------------------------------------------------------------------
__global__ __launch_bounds__(256) void p_encwt(const float* __restrict__ encW,
                                               u16* __restrict__ eT)
{
    __shared__ float tile[64][65];
    const int t = blockIdx.x;
    const int n0 = blockIdx.y * 64;
    const int tid = threadIdx.x;
    const int j = tid & 63, cg = tid >> 6;
    #pragma unroll
    for (int pass = 0; pass < 16; ++pass) {
        int c = pass * 4 + cg;
        float v = 0.f;
        if (t < T_N && n0 + j < EMB_N)
            v = encW[((size_t)c * T_N + t) * EMB_N + n0 + j];
        tile[c][j] = v;
    }
    __syncthreads();
    #pragma unroll
    for (int pass = 0; pass < 16; ++pass) {
        int nl = pass * 4 + cg;
        eT[(size_t)(n0 + nl) * KP2 + t * 64 + j] = f2bf(tile[j][nl]);
    }
}

// ---------------------------------------------------------------------------
// p_w1t: W1 f32 [184][1024] -> w1t bf16 [1024][192] (k pad zero)
// ---------------------------------------------------------------------------
__global__ __launch_bounds__(256) void p_w1t(const float* __restrict__ W1,
                                             u16* __restrict__ w1t)
{
    __shared__ float tile[64][65];
    const int k0 = blockIdx.x * 64, n0 = blockIdx.y * 64;
    for (int l = threadIdx.x; l < 4096; l += 256) {
        int i = l >> 6, j = l & 63;
        float v = (k0 + i < EMB_N) ? W1[(size_t)(k0 + i) * PROJ_N + n0 + j] : 0.f;
        tile[i][j] = v;
    }
    __syncthreads();
    for (int l = threadIdx.x; l < 4096; l += 256) {
        int j = l >> 6, i = l & 63;
        w1t[(size_t)(n0 + j) * EMBP + k0 + i] = f2bf(tile[i][j]);
    }
}

// ---------------------------------------------------------------------------
// p_w2t: W2 f32 [1024][1024] -> w2t bf16 [1024][1024] transposed
// ---------------------------------------------------------------------------
__global__ __launch_bounds__(256) void p_w2t(const float* __restrict__ W2,
                                             u16* __restrict__ w2t)
{
    __shared__ float tile[64][65];
    const int k0 = blockIdx.x * 64, n0 = blockIdx.y * 64;
    for (int l = threadIdx.x; l < 4096; l += 256) {
        int i = l >> 6, j = l & 63;
        tile[i][j] = W2[(size_t)(k0 + i) * PROJ_N + n0 + j];
    }
    __syncthreads();
    for (int l = threadIdx.x; l < 4096; l += 256) {
        int j = l >> 6, i = l & 63;
        w2t[(size_t)(n0 + j) * PROJ_N + k0 + i] = f2bf(tile[i][j]);
    }
}

// ---------------------------------------------------------------------------
// k1: zero-LDS MFMA. x[b,c,u] = sum_t eegb[b,c,t]*Wb[s,u,t] + bias
// out xb bf16 [b][u(288)][c(64)]; u>=275 rows zero.
// one block per b, 4 waves (2 wr x 2 wc), wave tile 32c x 144u.
// ---------------------------------------------------------------------------
__global__ __launch_bounds__(256) void k1_mfma(
    const u16* __restrict__ eegb, const int* __restrict__ sid,
    const u16* __restrict__ Wb, const float* __restrict__ subj_b,
    u16* __restrict__ xb)
{
    const int b = blockIdx.x;
    const int s = sid[b];
    const int tid = threadIdx.x;
    const int w = tid >> 6, lane = tid & 63;
    const int wr = w >> 1, wc = w & 1;
    const int lrow = lane & 15, lk = lane >> 4;
    const u16* A = eegb + (size_t)b * C_N * TPAD;
    const u16* Wr = Wb + (size_t)s * TP * TPAD;

    f32x4 acc[2][9] = {};
    for (int ks = 0; ks < 9; ++ks) {
        const int t0 = ks * 32 + 8 * lk;
        short8 af0 = *reinterpret_cast<const short8*>(A + (32 * wr + lrow) * TPAD + t0);
        short8 af1 = *reinterpret_cast<const short8*>(A + (32 * wr + 16 + lrow) * TPAD + t0);
        #pragma unroll
        for (int ct = 0; ct < 9; ++ct) {
            int u = 144 * wc + 16 * ct + lrow;
            short8 bf = *reinterpret_cast<const short8*>(Wr + (size_t)u * TPAD + t0);
            acc[0][ct] = MFMA16(af0, bf, acc[0][ct]);
            acc[1][ct] = MFMA16(af1, bf, acc[1][ct]);
        }
    }
    // epilogue: lane's 4 regs are 4 consecutive c at fixed u -> 8B stores
    #pragma unroll
    for (int ct = 0; ct < 9; ++ct) {
        int u = 144 * wc + 16 * ct + lrow;
        float bias = (u < T_N) ? subj_b[s * T_N + u] : 0.f;
        bool valid = (u < T_N);
        #pragma unroll
        for (int rt = 0; rt < 2; ++rt) {
            int c0 = 32 * wr + 16 * rt + 4 * lk;
            short4v pk;
            #pragma unroll
            for (int r = 0; r < 4; ++r)
                pk[r] = valid ? (short)f2bf(acc[rt][ct][r] + bias) : (short)0;
            *reinterpret_cast<short4v*>(xb + ((size_t)b * TP + u) * C_N + c0) = pk;
        }
    }
}

// ---------------------------------------------------------------------------
// k2: part[kz,m,n] = sum_{k chunk} xb[m,k'] * eT[n,k']
// grid (16 m-tiles of 64, 32 kz), 256 thr (4 waves, N-split).
// A staged via global_load_lds (swizzled source), B direct from L2.
// BK=64, 9 steps, double-buffered.
// ---------------------------------------------------------------------------
__global__ __launch_bounds__(256) void k2_mfma(
    const u16* __restrict__ xb, const u16* __restrict__ eT,
    float* __restrict__ part)
{
    __shared__ u16 Abuf[2][64 * 64];      // 8KB each
    const int m0 = blockIdx.x * 64;
    const int kz = blockIdx.y;
    const int tid = threadIdx.x;
    const int w = tid >> 6, lane = tid & 63;
    const int lrow = lane & 15, lk = lane >> 4;
    const int kbase = kz * KC2;

    // stage mapping: two issues per thread per step; chunk L covers [64 rows][8 chunks]
    const int r0 = tid >> 3, q0 = tid & 7;           // L0 = tid
    const int r1 = (tid + 256) >> 3, q1 = tid & 7;   // L1 = tid+256
    const u16* a0 = xb + (size_t)(m0 + r0) * KP2 + (q0 ^ (r0 & 7)) * 8;
    const u16* a1 = xb + (size_t)(m0 + r1) * KP2 + (q1 ^ (r1 & 7)) * 8;

    f32x4 acc[4][3] = {};
    int buf = 0;

    // prologue
    gload16(a0 + kbase, &Abuf[0][(size_t)(w * 64) * 8]);
    gload16(a1 + kbase, &Abuf[0][(size_t)(w * 64 + 256) * 8]);
    __syncthreads();

    for (int step = 0; step < 9; ++step) {
        if (step < 8) {
            int k0 = kbase + (step + 1) * 64;
            gload16(a0 + k0, &Abuf[buf ^ 1][(size_t)(w * 64) * 8]);
            gload16(a1 + k0, &Abuf[buf ^ 1][(size_t)(w * 64 + 256) * 8]);
        }
        short8 bf[3][2];
        #pragma unroll
        for (int ct = 0; ct < 3; ++ct)
            #pragma unroll
            for (int ki = 0; ki < 2; ++ki)
                bf[ct][ki] = *reinterpret_cast<const short8*>(
                    eT + (size_t)(48 * w + 16 * ct + lrow) * KP2 + kbase + step * 64 + ki * 32 + 8 * lk);
        #pragma unroll
        for (int rt = 0; rt < 4; ++rt) {
            int c = 16 * rt + lrow;
            #pragma unroll
            for (int ki = 0; ki < 2; ++ki) {
                short8 af = *reinterpret_cast<const short8*>(
                    &Abuf[buf][c * 64 + (((lk + 4 * ki) ^ (c & 7)) * 8)]);
                #pragma unroll
                for (int ct = 0; ct < 3; ++ct)
                    acc[rt][ct] = MFMA16(af, bf[ct][ki], acc[rt][ct]);
            }
        }
        __syncthreads();
        buf ^= 1;
    }

    #pragma unroll
    for (int rt = 0; rt < 4; ++rt)
        #pragma unroll
        for (int ct = 0; ct < 3; ++ct) {
            int n = 48 * w + 16 * ct + lrow;
            #pragma unroll
            for (int r = 0; r < 4; ++r) {
                int m = m0 + 16 * rt + 4 * lk + r;
                part[((size_t)kz * B_N + m) * EMBP + n] = acc[rt][ct][r];
            }
        }
}

// ---------------------------------------------------------------------------
// k3: hb[m,n] = bf16(enc_b[n] + sum_z part[z,m,n]); n>=184 -> 0
// ---------------------------------------------------------------------------
__global__ __launch_bounds__(256) void k3_reduce(
    const float* __restrict__ part, const float* __restrict__ enc_b,
    u16* __restrict__ hb)
{
    int idx = blockIdx.x * 256 + threadIdx.x;
    if (idx >= B_N * EMBP) return;
    int n = idx % EMBP;
    float s = 0.f;
    if (n < EMB_N) {
        s = enc_b[n];
        #pragma unroll
        for (int z = 0; z < KZ2; ++z)
            s += part[(size_t)z * B_N * EMBP + idx];
    }
    hb[idx] = f2bf(s);
}

// ---------------------------------------------------------------------------
// k4: h1 = hb @ W1 + b1 (K=192, full-K staged); g = bf16(gelu(h1))
// grid (16,16), 256 thr, 4 waves 2x2, wave tile 32x32
// ---------------------------------------------------------------------------
__global__ __launch_bounds__(256) void k4_mfma(
    const u16* __restrict__ hb, const u16* __restrict__ w1t,
    const float* __restrict__ b1, float* __restrict__ h1, u16* __restrict__ g)
{
    __shared__ u16 Ab[64 * EMBP];   // 24KB
    __shared__ u16 Bb[64 * EMBP];   // 24KB
    const int m0 = blockIdx.x * 64, n0 = blockIdx.y * 64;
    const int tid = threadIdx.x;
    const int w = tid >> 6, lane = tid & 63;
    const int wr = w >> 1, wc = w & 1;
    const int lrow = lane & 15, lk = lane >> 4;

    // stage: 1536 chunks per operand, 6 per thread
    #pragma unroll
    for (int i = 0; i < 6; ++i) {
        int L = tid + i * 256;
        int row = L / 24, qp = L % 24;
        int ql = qp ^ (row & 7);
        gload16(hb  + (size_t)(m0 + row) * EMBP + ql * 8, &Ab[(size_t)(w * 64 + i * 256) * 8]);
        gload16(w1t + (size_t)(n0 + row) * EMBP + ql * 8, &Bb[(size_t)(w * 64 + i * 256) * 8]);
    }
    __syncthreads();

    f32x4 acc[2][2] = {};
    #pragma unroll
    for (int ks = 0; ks < 6; ++ks) {
        #pragma unroll
        for (int rt = 0; rt < 2; ++rt) {
            int c = 32 * wr + 16 * rt + lrow;
            short8 af = *reinterpret_cast<const short8*>(
                &Ab[c * EMBP + (((4 * ks + lk) ^ (c & 7)) * 8)]);
            #pragma unroll
            for (int ct = 0; ct < 2; ++ct) {
                int nl = 32 * wc + 16 * ct + lrow;
                short8 bfv = *reinterpret_cast<const short8*>(
                    &Bb[nl * EMBP + (((4 * ks + lk) ^ (nl & 7)) * 8)]);
                acc[rt][ct] = MFMA16(af, bfv, acc[rt][ct]);
            }
        }
    }
    #pragma unroll
    for (int rt = 0; rt < 2; ++rt)
        #pragma unroll
        for (int ct = 0; ct < 2; ++ct) {
            int n = n0 + 32 * wc + 16 * ct + lrow;
            #pragma unroll
            for (int r = 0; r < 4; ++r) {
                int m = m0 + 32 * wr + 16 * rt + 4 * lk + r;
                float v = acc[rt][ct][r] + b1[n];
                size_t o = (size_t)m * PROJ_N + n;
                h1[o] = v;
                g[o] = f2bf(gelu_exact(v));
            }
        }
}

// ---------------------------------------------------------------------------
// k5: part2[kz] = g @ W2 chunk (K=512 each), BK=64, dbuf
// grid (16,16,2), 256 thr, 4 waves 2x2
// ---------------------------------------------------------------------------
__global__ __launch_bounds__(256) void k5_mfma(
    const u16* __restrict__ g, const u16* __restrict__ w2t,
    float* __restrict__ part2)
{
    __shared__ u16 Ab[2][64 * 64];
    __shared__ u16 Bb[2][64 * 64];
    const int m0 = blockIdx.x * 64, n0 = blockIdx.y * 64;
    const int kz = blockIdx.z;
    const int kbase = kz * (PROJ_N / KZ5);
    const int tid = threadIdx.x;
    const int w = tid >> 6, lane = tid & 63;
    const int wr = w >> 1, wc = w & 1;
    const int lrow = lane & 15, lk = lane >> 4;

    const int r0 = tid >> 3, q0 = tid & 7;
    const int r1 = (tid + 256) >> 3;
    const u16* a0 = g + (size_t)(m0 + r0) * PROJ_N + (q0 ^ (r0 & 7)) * 8;
    const u16* a1 = g + (size_t)(m0 + r1) * PROJ_N + (q0 ^ (r1 & 7)) * 8;
    const u16* b0 = w2t + (size_t)(n0 + r0) * PROJ_N + (q0 ^ (r0 & 7)) * 8;
    const u16* b1p = w2t + (size_t)(n0 + r1) * PROJ_N + (q0 ^ (r1 & 7)) * 8;

    f32x4 acc[2][2] = {};
    int buf = 0;
    gload16(a0 + kbase, &Ab[0][(size_t)(w * 64) * 8]);
    gload16(a1 + kbase, &Ab[0][(size_t)(w * 64 + 256) * 8]);
    gload16(b0 + kbase, &Bb[0][(size_t)(w * 64) * 8]);
    gload16(b1p + kbase, &Bb[0][(size_t)(w * 64 + 256) * 8]);
    __syncthreads();

    for (int step = 0; step < 8; ++step) {
        if (step < 7) {
            int k0 = kbase + (step + 1) * 64;
            gload16(a0 + k0, &Ab[buf ^ 1][(size_t)(w * 64) * 8]);
            gload16(a1 + k0, &Ab[buf ^ 1][(size_t)(w * 64 + 256) * 8]);
            gload16(b0 + k0, &Bb[buf ^ 1][(size_t)(w * 64) * 8]);
            gload16(b1p + k0, &Bb[buf ^ 1][(size_t)(w * 64 + 256) * 8]);
        }
        #pragma unroll
        for (int ki = 0; ki < 2; ++ki) {
            #pragma unroll
            for (int rt = 0; rt < 2; ++rt) {
                int c = 32 * wr + 16 * rt + lrow;
                short8 af = *reinterpret_cast<const short8*>(
                    &Ab[buf][c * 64 + (((lk + 4 * ki) ^ (c & 7)) * 8)]);
                #pragma unroll
                for (int ct = 0; ct < 2; ++ct) {
                    int nl = 32 * wc + 16 * ct + lrow;
                    short8 bfv = *reinterpret_cast<const short8*>(
                        &Bb[buf][nl * 64 + (((lk + 4 * ki) ^ (nl & 7)) * 8)]);
                    acc[rt][ct] = MFMA16(af, bfv, acc[rt][ct]);
                }
            }
        }
        __syncthreads();
        buf ^= 1;
    }
    #pragma unroll
    for (int rt = 0; rt < 2; ++rt)
        #pragma unroll
        for (int ct = 0; ct < 2; ++ct) {
            int n = n0 + 32 * wc + 16 * ct + lrow;
            #pragma unroll
            for (int r = 0; r < 4; ++r) {
                int m = m0 + 32 * wr + 16 * rt + 4 * lk + r;
                part2[(size_t)kz * B_N * PROJ_N + (size_t)m * PROJ_N + n] = acc[rt][ct][r];
            }
        }
}

// ---------------------------------------------------------------------------
// k5r_ln: hr = h1 + (part2[0]+part2[1]+b2); out = LN(hr)*gamma+beta
// one block per row
// ---------------------------------------------------------------------------
__global__ __launch_bounds__(256) void k5r_ln(
    const float* __restrict__ part2, const float* __restrict__ h1,
    const float* __restrict__ b2, const float* __restrict__ gamma,
    const float* __restrict__ beta, float* __restrict__ out)
{
    const int m = blockIdx.x;
    const int tid = threadIdx.x;
    const float4* h4 = reinterpret_cast<const float4*>(h1 + (size_t)m * PROJ_N);
    const float4* p0 = reinterpret_cast<const float4*>(part2 + (size_t)m * PROJ_N);
    const float4* p1 = reinterpret_cast<const float4*>(part2 + (size_t)(B_N + m) * PROJ_N);
    const float4* b4 = reinterpret_cast<const float4*>(b2);
    float4 va = h4[tid], vb = p0[tid], vc = p1[tid], vd = b4[tid];
    float v[4] = { va.x + vb.x + vc.x + vd.x, va.y + vb.y + vc.y + vd.y,
                   va.z + vb.z + vc.z + vd.z, va.w + vb.w + vc.w + vd.w };
    float s = 0.f, sq = 0.f;
    #pragma unroll
    for (int i = 0; i < 4; ++i) { s += v[i]; sq += v[i] * v[i]; }
    #pragma unroll
    for (int off = 32; off > 0; off >>= 1) {
        s  += __shfl_down(s, off);
        sq += __shfl_down(sq, off);
    }
    __shared__ float ss[4], ssq[4];
    int wid = tid >> 6, lane = tid & 63;
    if (lane == 0) { ss[wid] = s; ssq[wid] = sq; }
    __syncthreads();
    if (tid == 0) {
        float a = 0.f, bsum = 0.f;
        #pragma unroll
        for (int q = 0; q < 4; ++q) { a += ss[q]; bsum += ssq[q]; }
        ss[0] = a; ssq[0] = bsum;
    }
    __syncthreads();
    float mu  = ss[0] * (1.0f / PROJ_N);
    float var = ssq[0] * (1.0f / PROJ_N) - mu * mu;
    float rs  = rsqrtf(var + 1e-5f);
    const float4 g4 = reinterpret_cast<const float4*>(gamma)[tid];
    const float4 be4 = reinterpret_cast<const float4*>(beta)[tid];
    float gg[4] = { g4.x, g4.y, g4.z, g4.w };
    float bb[4] = { be4.x, be4.y, be4.z, be4.w };
    float4 o4;
    float* op = reinterpret_cast<float*>(&o4);
    #pragma unroll
    for (int i = 0; i < 4; ++i) op[i] = (v[i] - mu) * rs * gg[i] + bb[i];
    reinterpret_cast<float4*>(out + (size_t)m * PROJ_N)[tid] = o4;
}

// ---------------------------------------------------------------------------
extern "C" void kernel_launch(void* const* d_in, const int* in_sizes, int n_in,
                              void* d_out, int out_size, void* d_ws, size_t ws_size,
                              hipStream_t stream)
{
    const float* eeg    = (const float*)d_in[0];
    const int*   sid    = (const int*)  d_in[1];
    const float* subj_W = (const float*)d_in[2];
    const float* subj_b = (const float*)d_in[3];
    const float* enc_W  = (const float*)d_in[4];
    const float* enc_b  = (const float*)d_in[5];
    const float* W1     = (const float*)d_in[6];
    const float* b1     = (const float*)d_in[7];
    const float* W2     = (const float*)d_in[8];
    const float* b2     = (const float*)d_in[9];
    const float* gamma  = (const float*)d_in[10];
    const float* beta   = (const float*)d_in[11];
    float* out = (float*)d_out;

    char* w = (char*)d_ws;
    u16*   xb    = (u16*)(w);                       // 37,748,736
    u16*   Wb    = (u16*)(w + 37748736);            //  1,704,960
    u16*   eT    = (u16*)(w + 39453696);            //  7,077,888
    u16*   w1t   = (u16*)(w + 46531584);            //    393,216
    u16*   w2t   = (u16*)(w + 46924800);            //  2,097,152
    u16*   hb    = (u16*)(w + 49021952);            //    393,216
    float* h1    = (float*)(w + 49415168);          //  4,194,304
    u16*   g     = (u16*)(w + 53609472);            //  2,097,152
    char*  scr   = w + 55706624;                    // 38,797,376 scratch
    u16*   eegb  = (u16*)scr;                       // 38,797,312 (k1 only)
    float* part  = (float*)scr;                     // 25,165,824 (k2->k3, after k1)
    float* part2 = (float*)(scr + 25165824);        //  8,388,608 (k5->k5r)

    p_eeg   <<<dim3(B_N), 256, 0, stream>>>(eeg, eegb);
    p_wbf16 <<<dim3((S_N * TP * TPAD / 4 + 255) / 256), 256, 0, stream>>>(subj_W, Wb);
    p_encwt <<<dim3(TP, 3), 256, 0, stream>>>(enc_W, eT);
    p_w1t   <<<dim3(EMBP / 64, PROJ_N / 64), 256, 0, stream>>>(W1, w1t);
    p_w2t   <<<dim3(PROJ_N / 64, PROJ_N / 64), 256, 0, stream>>>(W2, w2t);

    k1_mfma <<<dim3(B_N), 256, 0, stream>>>(eegb, sid, Wb, subj_b, xb);
    k2_mfma <<<dim3(16, KZ2), 256, 0, stream>>>(xb, eT, part);
    k3_reduce<<<dim3((B_N * EMBP + 255) / 256), 256, 0, stream>>>(part, enc_b, hb);
    k4_mfma <<<dim3(16, 16), 256, 0, stream>>>(hb, w1t, b1, h1, g);
    k5_mfma <<<dim3(16, 16, KZ5), 256, 0, stream>>>(g, w2t, part2);
    k5r_ln  <<<dim3(B_N), 256, 0, stream>>>(part2, h1, b2, gamma, beta, out);
}

// Round 4
// 132.172 us; speedup vs baseline: 5.0843x; 1.0833x over previous
//
#include <hip/hip_runtime.h>
#include <math.h>

#define B_N    1024
#define C_N    64
#define T_N    275
#define S_N    10
#define EMB_N  184
#define PROJ_N 1024
#define CT_N   (C_N * T_N)      // 17600
#define TP     288              // padded T (9*32): K extent and u extent
#define KP2    (TP * C_N)       // 18432 = k2 K dim (u*64+c)
#define EMBP   192
#define KZ2    32
#define KC2    (KP2 / KZ2)      // 576
#define KZ5    2
#define GMAX   264              // max groups of 4 (padded per subject)

typedef unsigned short u16;
typedef __attribute__((ext_vector_type(8))) short short8;
typedef __attribute__((ext_vector_type(4))) short short4v;
typedef __attribute__((ext_vector_type(4))) float f32x4;

#define MFMA16(a,b,c) __builtin_amdgcn_mfma_f32_16x16x32_bf16(a, b, c, 0, 0, 0)

__device__ __forceinline__ u16 f2bf(float f) {
    union { float f; unsigned u; } v; v.f = f;
    unsigned r = v.u + 0x7FFFu + ((v.u >> 16) & 1u);   // RNE
    return (u16)(r >> 16);
}
__device__ __forceinline__ float gelu_exact(float v) {
    return 0.5f * v * (1.0f + erff(v * 0.70710678118654752f));
}
__device__ __forceinline__ void gload16(const void* g, void* lds) {
    __builtin_amdgcn_global_load_lds(
        (const __attribute__((address_space(1))) void*)g,
        (__attribute__((address_space(3))) void*)lds, 16, 0, 0);
}

// ---------------------------------------------------------------------------
// p_all: fused prep. Sectors by blockIdx.x:
//  [0,1024)      p_eeg   : eeg f32 -> eegb bf16 [b][64][288] (t pad zero)
//  [1024,1834)   p_wbf16 : subj_W -> Wb bf16 [10][288][288] (u,t pads zero)
//  [1834,2698)   p_encwt : enc_W -> eT bf16 [192][18432=t*64+c] (pads zero)
//  [2698,2746)   p_w1t   : W1 -> w1t bf16 [1024][192] (k pad zero)
//  [2746,3002)   p_w2t   : W2 -> w2t bf16 [1024][1024] transposed
//  3002          p_group : deterministic subject grouping -> bsq[1056]
// ---------------------------------------------------------------------------
__global__ __launch_bounds__(256) void p_all(
    const float* __restrict__ eeg, const int* __restrict__ sid,
    const float* __restrict__ W, const float* __restrict__ encW,
    const float* __restrict__ W1, const float* __restrict__ W2,
    u16* __restrict__ eegb, u16* __restrict__ Wb, u16* __restrict__ eT,
    u16* __restrict__ w1t, u16* __restrict__ w2t, int* __restrict__ bsq)
{
    __shared__ char smem[16640];
    const int blk = blockIdx.x;
    const int tid = threadIdx.x;

    if (blk < 1024) {                       // ---- p_eeg ----
        const int b = blk;
        const float* src = eeg + (size_t)b * CT_N;
        u16* dst = eegb + (size_t)b * C_N * TP;
        #pragma unroll
        for (int p = 0; p < 9; ++p) {       // 64*288/8 = 2304 chunks
            int ch = tid + p * 256;
            int c = ch / 36, q8 = ch - c * 36;
            int t0 = q8 * 8;
            short8 pk;
            #pragma unroll
            for (int e = 0; e < 8; ++e) {
                int t = t0 + e;
                float v = (t < T_N) ? src[c * T_N + t] : 0.f;
                pk[e] = (short)f2bf(v);
            }
            *reinterpret_cast<short8*>(dst + c * TP + t0) = pk;
        }
        return;
    }
    if (blk < 1834) {                       // ---- p_wbf16 ----
        int idx4 = (blk - 1024) * 256 + tid;
        if (idx4 >= S_N * TP * TP / 4) return;
        int o = idx4 * 4;
        int row = o / TP, t = o - row * TP;   // row = s*288+u
        int s = row / TP, u = row - s * TP;
        short4v pk;
        #pragma unroll
        for (int e = 0; e < 4; ++e) {
            float v = (u < T_N && t + e < T_N)
                ? W[((size_t)s * T_N + u) * T_N + t + e] : 0.f;
            pk[e] = (short)f2bf(v);
        }
        *reinterpret_cast<short4v*>(Wb + o) = pk;
        return;
    }
    if (blk < 2698) {                       // ---- p_encwt ----
        float (*tile)[65] = (float(*)[65])smem;
        int local = blk - 1834;
        const int t = local / 3;
        const int n0 = (local % 3) * 64;
        const int j = tid & 63, cg = tid >> 6;
        #pragma unroll
        for (int pass = 0; pass < 16; ++pass) {
            int c = pass * 4 + cg;
            float v = 0.f;
            if (t < T_N && n0 + j < EMB_N)
                v = encW[((size_t)c * T_N + t) * EMB_N + n0 + j];
            tile[c][j] = v;
        }
        __syncthreads();
        #pragma unroll
        for (int pass = 0; pass < 16; ++pass) {
            int nl = pass * 4 + cg;
            eT[(size_t)(n0 + nl) * KP2 + t * 64 + j] = f2bf(tile[j][nl]);
        }
        return;
    }
    if (blk < 2746) {                       // ---- p_w1t ----
        float (*tile)[65] = (float(*)[65])smem;
        int local = blk - 2698;
        const int k0 = (local % 3) * 64, n0 = (local / 3) * 64;
        for (int l = tid; l < 4096; l += 256) {
            int i = l >> 6, j = l & 63;
            float v = (k0 + i < EMB_N) ? W1[(size_t)(k0 + i) * PROJ_N + n0 + j] : 0.f;
            tile[i][j] = v;
        }
        __syncthreads();
        for (int l = tid; l < 4096; l += 256) {
            int j = l >> 6, i = l & 63;
            w1t[(size_t)(n0 + j) * EMBP + k0 + i] = f2bf(tile[i][j]);
        }
        return;
    }
    if (blk < 3002) {                       // ---- p_w2t ----
        float (*tile)[65] = (float(*)[65])smem;
        int local = blk - 2746;
        const int k0 = (local % 16) * 64, n0 = (local / 16) * 64;
        for (int l = tid; l < 4096; l += 256) {
            int i = l >> 6, j = l & 63;
            tile[i][j] = W2[(size_t)(k0 + i) * PROJ_N + n0 + j];
        }
        __syncthreads();
        for (int l = tid; l < 4096; l += 256) {
            int j = l >> 6, i = l & 63;
            w2t[(size_t)(n0 + j) * PROJ_N + k0 + i] = f2bf(tile[i][j]);
        }
        return;
    }
    // ---- p_group: bucket b's by subject, groups padded to 4, slots -1 ----
    {
        int* sgrp = (int*)smem;                 // [1024]
        int* C    = (int*)(smem + 4096);        // [16][10]
        int* tot  = (int*)(smem + 4096 + 640);  // [10]
        for (int i = tid; i < 1024; i += 256) sgrp[i] = sid[i];
        for (int i = tid; i < 4 * GMAX; i += 256) bsq[i] = -1;
        __syncthreads();
        const int w4 = tid >> 6, lane = tid & 63;
        #pragma unroll
        for (int j = 0; j < 4; ++j) {
            int chunk = w4 * 4 + j;
            int sb = sgrp[chunk * 64 + lane];
            int myc = 0;
            for (int s = 0; s < S_N; ++s) {
                unsigned long long m = __ballot(sb == s);
                if (lane == s) myc = (int)__popcll(m);
            }
            if (lane < S_N) C[chunk * S_N + lane] = myc;
        }
        __syncthreads();
        if (tid < S_N) {
            int a = 0;
            for (int w2 = 0; w2 < 16; ++w2) a += C[w2 * S_N + tid];
            tot[tid] = a;
        }
        __syncthreads();
        #pragma unroll
        for (int rep = 0; rep < 4; ++rep) {
            int b = tid + rep * 256;
            int s = sgrp[b];
            int off = 0;
            for (int s2 = 0; s2 < S_N; ++s2)
                if (s2 < s) off += (tot[s2] + 3) & ~3;
            int chunk = b >> 6;
            int rank = 0;
            for (int w2 = 0; w2 < 16; ++w2)
                if (w2 < chunk) rank += C[w2 * S_N + s];
            for (int i = chunk * 64; i < b; ++i) rank += (sgrp[i] == s) ? 1 : 0;
            bsq[off + rank] = b;
        }
    }
}

// ---------------------------------------------------------------------------
// k1g: subject-grouped MFMA. 512 thr = 8 waves = 4 b's x 2 u-halves.
// x[b,c,u] = sum_t eegb[b,c,t]*Wb[s,u,t] + bias -> xb bf16 [b][u:288][c:64]
// B tile staged once per block in LDS (dbuf, XOR-swizzled), A direct+prefetch.
// ---------------------------------------------------------------------------
__global__ __launch_bounds__(512, 2) void k1g(
    const u16* __restrict__ eegb, const int* __restrict__ sid,
    const u16* __restrict__ Wb, const float* __restrict__ subj_b,
    const int* __restrict__ bsq, u16* __restrict__ xb)
{
    __shared__ u16 Bs[2][TP * 4 * 8];       // 2 x [288 rows][4 chunks][8 bf16] = 36KB
    const int g = blockIdx.x;
    const int b0 = bsq[g * 4];
    if (b0 < 0) return;                      // empty group (uniform)
    const int s = sid[b0];
    const int tid = threadIdx.x;
    const int w = tid >> 6, lane = tid & 63;
    const int bi = w >> 1, uh = w & 1;
    const int lrow = lane & 15, lk = lane >> 4;
    const int b = bsq[g * 4 + bi];
    const int bsafe = (b >= 0) ? b : 0;
    const u16* A = eegb + (size_t)bsafe * C_N * TP;
    const u16* Wr = Wb + (size_t)s * TP * TP;

    // stage B [288][32] for K-step ks into buffer st (swizzle q^=((u>>1)&3))
    #define K1_STAGE(st, ks)                                                   \
        for (int l = tid; l < TP * 4; l += 512) {                              \
            int u_ = l >> 2, q_ = l & 3;                                       \
            gload16(Wr + (size_t)u_ * TP + (ks) * 32 + ((q_ ^ ((u_ >> 1) & 3)) << 3), \
                    &Bs[st][l * 8]);                                           \
        }

    f32x4 acc[4][9] = {};
    short8 a[4], an[4];

    K1_STAGE(0, 0);
    #pragma unroll
    for (int rt = 0; rt < 4; ++rt)
        a[rt] = *reinterpret_cast<const short8*>(A + (16 * rt + lrow) * TP + 8 * lk);
    __syncthreads();

    for (int ks = 0; ks < 9; ++ks) {
        const int st = ks & 1;
        if (ks < 8) {
            K1_STAGE(st ^ 1, ks + 1);
            #pragma unroll
            for (int rt = 0; rt < 4; ++rt)
                an[rt] = *reinterpret_cast<const short8*>(
                    A + (16 * rt + lrow) * TP + (ks + 1) * 32 + 8 * lk);
        }
        #pragma unroll
        for (int ct = 0; ct < 9; ++ct) {
            int u = uh * 144 + 16 * ct + lrow;
            int chunk = u * 4 + (lk ^ ((u >> 1) & 3));
            short8 bv = *reinterpret_cast<const short8*>(&Bs[st][chunk * 8]);
            #pragma unroll
            for (int rt = 0; rt < 4; ++rt)
                acc[rt][ct] = MFMA16(a[rt], bv, acc[rt][ct]);
        }
        __syncthreads();
        #pragma unroll
        for (int rt = 0; rt < 4; ++rt) a[rt] = an[rt];
    }

    if (b < 0) return;                      // sentinel wave: no store
    #pragma unroll
    for (int ct = 0; ct < 9; ++ct) {
        int u = uh * 144 + 16 * ct + lrow;
        if (u >= T_N) continue;
        float bias = subj_b[s * T_N + u];
        #pragma unroll
        for (int rt = 0; rt < 4; ++rt) {
            int c0 = 16 * rt + 4 * lk;
            short4v pk;
            #pragma unroll
            for (int r = 0; r < 4; ++r)
                pk[r] = (short)f2bf(acc[rt][ct][r] + bias);
            *reinterpret_cast<short4v*>(xb + ((size_t)b * TP + u) * C_N + c0) = pk;
        }
    }
    #undef K1_STAGE
}

// ---------------------------------------------------------------------------
// k2: part[kz,m,n] = sum_{k chunk} xb[m,k'] * eT[n,k']
// grid (8 m-tiles of 128, 32 kz), 256 thr, 4 waves N-split (48 n each).
// A gload_lds dbuf swizzled; B direct from L2 with prefetch. BK=64, 9 steps.
// ---------------------------------------------------------------------------
__global__ __launch_bounds__(256) void k2_mfma(
    const u16* __restrict__ xb, const u16* __restrict__ eT,
    float* __restrict__ part)
{
    __shared__ u16 Ab[2][128 * 64];         // 16 KB each
    const int m0 = blockIdx.x * 128;
    const int kz = blockIdx.y;
    const int kbase = kz * KC2;
    const int tid = threadIdx.x;
    const int w = tid >> 6, lane = tid & 63;
    const int lrow = lane & 15, lk = lane >> 4;

    #define K2_STAGE(st, step)                                                 \
        _Pragma("unroll")                                                      \
        for (int p = 0; p < 4; ++p) {                                          \
            int l = tid + p * 256;                                             \
            int r_ = l >> 3, q_ = l & 7;                                       \
            gload16(xb + (size_t)(m0 + r_) * KP2 + kbase + (step) * 64 +       \
                        ((q_ ^ (r_ & 7)) << 3),                                \
                    &Ab[st][l * 8]);                                           \
        }

    #define K2_BLOAD(step, dst)                                                \
        _Pragma("unroll")                                                      \
        for (int ct = 0; ct < 3; ++ct)                                         \
            _Pragma("unroll")                                                  \
            for (int ki = 0; ki < 2; ++ki)                                     \
                dst[ct][ki] = *reinterpret_cast<const short8*>(                \
                    eT + (size_t)(48 * w + 16 * ct + lrow) * KP2 + kbase +     \
                    (step) * 64 + ki * 32 + 8 * lk);

    f32x4 acc[8][3] = {};
    short8 bf[3][2], bn[3][2];

    K2_STAGE(0, 0);
    K2_BLOAD(0, bf);
    __syncthreads();

    for (int step = 0; step < 9; ++step) {
        const int st = step & 1;
        if (step < 8) {
            K2_STAGE(st ^ 1, step + 1);
            K2_BLOAD(step + 1, bn);
        }
        #pragma unroll
        for (int ki = 0; ki < 2; ++ki)
            #pragma unroll
            for (int rt = 0; rt < 8; ++rt) {
                int m = 16 * rt + lrow;
                int chunk = m * 8 + ((4 * ki + lk) ^ (m & 7));
                short8 af = *reinterpret_cast<const short8*>(&Ab[st][chunk * 8]);
                #pragma unroll
                for (int ct = 0; ct < 3; ++ct)
                    acc[rt][ct] = MFMA16(af, bf[ct][ki], acc[rt][ct]);
            }
        __syncthreads();
        #pragma unroll
        for (int ct = 0; ct < 3; ++ct)
            #pragma unroll
            for (int ki = 0; ki < 2; ++ki) bf[ct][ki] = bn[ct][ki];
    }

    #pragma unroll
    for (int rt = 0; rt < 8; ++rt)
        #pragma unroll
        for (int ct = 0; ct < 3; ++ct) {
            int n = 48 * w + 16 * ct + lrow;
            #pragma unroll
            for (int r = 0; r < 4; ++r) {
                int m = m0 + 16 * rt + 4 * lk + r;
                part[((size_t)kz * B_N + m) * EMBP + n] = acc[rt][ct][r];
            }
        }
    #undef K2_STAGE
    #undef K2_BLOAD
}

// ---------------------------------------------------------------------------
// k3: hb[m,n] = bf16(enc_b[n] + sum_z part[z,m,n]); n>=184 -> 0
// ---------------------------------------------------------------------------
__global__ __launch_bounds__(256) void k3_reduce(
    const float* __restrict__ part, const float* __restrict__ enc_b,
    u16* __restrict__ hb)
{
    int idx = blockIdx.x * 256 + threadIdx.x;
    if (idx >= B_N * EMBP) return;
    int n = idx % EMBP;
    float s = 0.f;
    if (n < EMB_N) {
        s = enc_b[n];
        #pragma unroll
        for (int z = 0; z < KZ2; ++z)
            s += part[(size_t)z * B_N * EMBP + idx];
    }
    hb[idx] = f2bf(s);
}

// ---------------------------------------------------------------------------
// k4: h1 = hb @ W1 + b1 (K=192); g = bf16(gelu(h1))
// ---------------------------------------------------------------------------
__global__ __launch_bounds__(256) void k4_mfma(
    const u16* __restrict__ hb, const u16* __restrict__ w1t,
    const float* __restrict__ b1, float* __restrict__ h1, u16* __restrict__ g)
{
    __shared__ u16 Ab[64 * EMBP];
    __shared__ u16 Bb[64 * EMBP];
    const int m0 = blockIdx.x * 64, n0 = blockIdx.y * 64;
    const int tid = threadIdx.x;
    const int w = tid >> 6, lane = tid & 63;
    const int wr = w >> 1, wc = w & 1;
    const int lrow = lane & 15, lk = lane >> 4;

    #pragma unroll
    for (int i = 0; i < 6; ++i) {
        int L = tid + i * 256;
        int row = L / 24, qp = L % 24;
        int ql = qp ^ (row & 7);
        gload16(hb  + (size_t)(m0 + row) * EMBP + ql * 8, &Ab[(size_t)L * 8]);
        gload16(w1t + (size_t)(n0 + row) * EMBP + ql * 8, &Bb[(size_t)L * 8]);
    }
    __syncthreads();

    f32x4 acc[2][2] = {};
    #pragma unroll
    for (int ks = 0; ks < 6; ++ks) {
        #pragma unroll
        for (int rt = 0; rt < 2; ++rt) {
            int c = 32 * wr + 16 * rt + lrow;
            short8 af = *reinterpret_cast<const short8*>(
                &Ab[c * EMBP + (((4 * ks + lk) ^ (c & 7)) * 8)]);
            #pragma unroll
            for (int ct = 0; ct < 2; ++ct) {
                int nl = 32 * wc + 16 * ct + lrow;
                short8 bfv = *reinterpret_cast<const short8*>(
                    &Bb[nl * EMBP + (((4 * ks + lk) ^ (nl & 7)) * 8)]);
                acc[rt][ct] = MFMA16(af, bfv, acc[rt][ct]);
            }
        }
    }
    #pragma unroll
    for (int rt = 0; rt < 2; ++rt)
        #pragma unroll
        for (int ct = 0; ct < 2; ++ct) {
            int n = n0 + 32 * wc + 16 * ct + lrow;
            #pragma unroll
            for (int r = 0; r < 4; ++r) {
                int m = m0 + 32 * wr + 16 * rt + 4 * lk + r;
                float v = acc[rt][ct][r] + b1[n];
                size_t o = (size_t)m * PROJ_N + n;
                h1[o] = v;
                g[o] = f2bf(gelu_exact(v));
            }
        }
}

// ---------------------------------------------------------------------------
// k5: part2[kz] = g @ W2 chunk (K=512 each), BK=64, dbuf
// ---------------------------------------------------------------------------
__global__ __launch_bounds__(256) void k5_mfma(
    const u16* __restrict__ g, const u16* __restrict__ w2t,
    float* __restrict__ part2)
{
    __shared__ u16 Ab[2][64 * 64];
    __shared__ u16 Bb[2][64 * 64];
    const int m0 = blockIdx.x * 64, n0 = blockIdx.y * 64;
    const int kz = blockIdx.z;
    const int kbase = kz * (PROJ_N / KZ5);
    const int tid = threadIdx.x;
    const int w = tid >> 6, lane = tid & 63;
    const int wr = w >> 1, wc = w & 1;
    const int lrow = lane & 15, lk = lane >> 4;

    const int r0 = tid >> 3, q0 = tid & 7;
    const int r1 = (tid + 256) >> 3;
    const u16* a0 = g + (size_t)(m0 + r0) * PROJ_N + (q0 ^ (r0 & 7)) * 8;
    const u16* a1 = g + (size_t)(m0 + r1) * PROJ_N + (q0 ^ (r1 & 7)) * 8;
    const u16* b0 = w2t + (size_t)(n0 + r0) * PROJ_N + (q0 ^ (r0 & 7)) * 8;
    const u16* b1p = w2t + (size_t)(n0 + r1) * PROJ_N + (q0 ^ (r1 & 7)) * 8;

    f32x4 acc[2][2] = {};
    int buf = 0;
    gload16(a0 + kbase, &Ab[0][(size_t)(w * 64) * 8]);
    gload16(a1 + kbase, &Ab[0][(size_t)(w * 64 + 256) * 8]);
    gload16(b0 + kbase, &Bb[0][(size_t)(w * 64) * 8]);
    gload16(b1p + kbase, &Bb[0][(size_t)(w * 64 + 256) * 8]);
    __syncthreads();

    for (int step = 0; step < 8; ++step) {
        if (step < 7) {
            int k0 = kbase + (step + 1) * 64;
            gload16(a0 + k0, &Ab[buf ^ 1][(size_t)(w * 64) * 8]);
            gload16(a1 + k0, &Ab[buf ^ 1][(size_t)(w * 64 + 256) * 8]);
            gload16(b0 + k0, &Bb[buf ^ 1][(size_t)(w * 64) * 8]);
            gload16(b1p + k0, &Bb[buf ^ 1][(size_t)(w * 64 + 256) * 8]);
        }
        #pragma unroll
        for (int ki = 0; ki < 2; ++ki) {
            #pragma unroll
            for (int rt = 0; rt < 2; ++rt) {
                int c = 32 * wr + 16 * rt + lrow;
                short8 af = *reinterpret_cast<const short8*>(
                    &Ab[buf][c * 64 + (((lk + 4 * ki) ^ (c & 7)) * 8)]);
                #pragma unroll
                for (int ct = 0; ct < 2; ++ct) {
                    int nl = 32 * wc + 16 * ct + lrow;
                    short8 bfv = *reinterpret_cast<const short8*>(
                        &Bb[buf][nl * 64 + (((lk + 4 * ki) ^ (nl & 7)) * 8)]);
                    acc[rt][ct] = MFMA16(af, bfv, acc[rt][ct]);
                }
            }
        }
        __syncthreads();
        buf ^= 1;
    }
    #pragma unroll
    for (int rt = 0; rt < 2; ++rt)
        #pragma unroll
        for (int ct = 0; ct < 2; ++ct) {
            int n = n0 + 32 * wc + 16 * ct + lrow;
            #pragma unroll
            for (int r = 0; r < 4; ++r) {
                int m = m0 + 32 * wr + 16 * rt + 4 * lk + r;
                part2[(size_t)kz * B_N * PROJ_N + (size_t)m * PROJ_N + n] = acc[rt][ct][r];
            }
        }
}

// ---------------------------------------------------------------------------
// k5r_ln: hr = h1 + (part2[0]+part2[1]+b2); out = LN(hr)*gamma+beta
// ---------------------------------------------------------------------------
__global__ __launch_bounds__(256) void k5r_ln(
    const float* __restrict__ part2, const float* __restrict__ h1,
    const float* __restrict__ b2, const float* __restrict__ gamma,
    const float* __restrict__ beta, float* __restrict__ out)
{
    const int m = blockIdx.x;
    const int tid = threadIdx.x;
    const float4* h4 = reinterpret_cast<const float4*>(h1 + (size_t)m * PROJ_N);
    const float4* p0 = reinterpret_cast<const float4*>(part2 + (size_t)m * PROJ_N);
    const float4* p1 = reinterpret_cast<const float4*>(part2 + (size_t)(B_N + m) * PROJ_N);
    const float4* b4 = reinterpret_cast<const float4*>(b2);
    float4 va = h4[tid], vb = p0[tid], vc = p1[tid], vd = b4[tid];
    float v[4] = { va.x + vb.x + vc.x + vd.x, va.y + vb.y + vc.y + vd.y,
                   va.z + vb.z + vc.z + vd.z, va.w + vb.w + vc.w + vd.w };
    float s = 0.f, sq = 0.f;
    #pragma unroll
    for (int i = 0; i < 4; ++i) { s += v[i]; sq += v[i] * v[i]; }
    #pragma unroll
    for (int off = 32; off > 0; off >>= 1) {
        s  += __shfl_down(s, off);
        sq += __shfl_down(sq, off);
    }
    __shared__ float ss[4], ssq[4];
    int wid = tid >> 6, lane = tid & 63;
    if (lane == 0) { ss[wid] = s; ssq[wid] = sq; }
    __syncthreads();
    if (tid == 0) {
        float a = 0.f, bsum = 0.f;
        #pragma unroll
        for (int q = 0; q < 4; ++q) { a += ss[q]; bsum += ssq[q]; }
        ss[0] = a; ssq[0] = bsum;
    }
    __syncthreads();
    float mu  = ss[0] * (1.0f / PROJ_N);
    float var = ssq[0] * (1.0f / PROJ_N) - mu * mu;
    float rs  = rsqrtf(var + 1e-5f);
    const float4 g4 = reinterpret_cast<const float4*>(gamma)[tid];
    const float4 be4 = reinterpret_cast<const float4*>(beta)[tid];
    float gg[4] = { g4.x, g4.y, g4.z, g4.w };
    float bb[4] = { be4.x, be4.y, be4.z, be4.w };
    float4 o4;
    float* op = reinterpret_cast<float*>(&o4);
    #pragma unroll
    for (int i = 0; i < 4; ++i) op[i] = (v[i] - mu) * rs * gg[i] + bb[i];
    reinterpret_cast<float4*>(out + (size_t)m * PROJ_N)[tid] = o4;
}

// ---------------------------------------------------------------------------
extern "C" void kernel_launch(void* const* d_in, const int* in_sizes, int n_in,
                              void* d_out, int out_size, void* d_ws, size_t ws_size,
                              hipStream_t stream)
{
    const float* eeg    = (const float*)d_in[0];
    const int*   sid    = (const int*)  d_in[1];
    const float* subj_W = (const float*)d_in[2];
    const float* subj_b = (const float*)d_in[3];
    const float* enc_W  = (const float*)d_in[4];
    const float* enc_b  = (const float*)d_in[5];
    const float* W1     = (const float*)d_in[6];
    const float* b1     = (const float*)d_in[7];
    const float* W2     = (const float*)d_in[8];
    const float* b2     = (const float*)d_in[9];
    const float* gamma  = (const float*)d_in[10];
    const float* beta   = (const float*)d_in[11];
    float* out = (float*)d_out;

    char* w = (char*)d_ws;
    u16*   xb    = (u16*)(w);                    // 37,748,736
    u16*   Wb    = (u16*)(w + 37748736);         //  1,658,880 (10*288*288*2)
    u16*   eT    = (u16*)(w + 39407616);         //  7,077,888
    u16*   w1t   = (u16*)(w + 46485504);         //    393,216
    u16*   w2t   = (u16*)(w + 46878720);         //  2,097,152
    u16*   hb    = (u16*)(w + 48975872);         //    393,216
    float* h1    = (float*)(w + 49369088);       //  4,194,304
    u16*   g     = (u16*)(w + 53563392);         //  2,097,152
    int*   bsq   = (int*)(w + 55660544);         //      4,352
    char*  scr   = w + 55664896;                 // 37,748,736 scratch
    u16*   eegb  = (u16*)scr;                    // 37,748,736 (k1g only)
    float* part  = (float*)scr;                  // 25,165,824 (k2->k3)
    float* part2 = (float*)(scr + 25165824);     //  8,388,608 (k5->k5r)

    p_all<<<dim3(3003), 256, 0, stream>>>(eeg, sid, subj_W, enc_W, W1, W2,
                                          eegb, Wb, eT, w1t, w2t, bsq);
    k1g  <<<dim3(GMAX), 512, 0, stream>>>(eegb, sid, Wb, subj_b, bsq, xb);
    k2_mfma<<<dim3(8, KZ2), 256, 0, stream>>>(xb, eT, part);
    k3_reduce<<<dim3((B_N * EMBP + 255) / 256), 256, 0, stream>>>(part, enc_b, hb);
    k4_mfma<<<dim3(16, 16), 256, 0, stream>>>(hb, w1t, b1, h1, g);
    k5_mfma<<<dim3(16, 16, KZ5), 256, 0, stream>>>(g, w2t, part2);
    k5r_ln <<<dim3(B_N), 256, 0, stream>>>(part2, h1, b2, gamma, beta, out);
}